// Round 2
// baseline (9413.776 us; speedup 1.0000x reference)
//
#include <hip/hip_runtime.h>
#include <stdint.h>
#include <math.h>

// ---------------- problem constants ----------------
#define BB 32
#define TT 1024
#define CIN 128
#define FF 256
#define KW 5
#define HH 512
#define TP 510          // conv output length (VALID, stride 2)
#define TLAST 509
#define NPAD 16384      // padded (t',b) count (512*32)
#define KC 640          // conv GEMM K  (5*128)
#define G4 2048         // 4*H
#define GWG 64          // scan workgroups (8 hidden units each)

// ---------------- workspace layout (bytes) ----------------
// sync region (memset to 0 every launch):
#define FLAGS_OFF   0u            // 64 flags, 64B stride -> 4096
#define HPK_OFF     4096u         // h packed u32 (hi<<16|lo), dbuf: 2*32*512*4 = 131072
#define PARTS_OFF   135168u       // du partials: 2*32*64*4 = 16384
#define SYNC_BYTES  151552u
// big buffers:
#define XP_OFF      151552ull                         // fp32 [2048][16384] = 134217728
#define XH_OFF      (XP_OFF + 134217728ull)           // x hi bf16 [4194304]
#define XL_OFF      (XH_OFF + 8388608ull)
#define XSH_OFF     (XL_OFF + 8388608ull)             // xs hi bf16 [16384][256]
#define XSL_OFF     (XSH_OFF + 8388608ull)
#define WCH_OFF     (XSL_OFF + 8388608ull)            // conv W [256][640] hi
#define WCL_OFF     (WCH_OFF + 327680ull)
#define WIHH_OFF    (WCL_OFF + 327680ull)             // w_ih [2048][256] hi
#define WIHL_OFF    (WIHH_OFF + 1048576ull)
#define WS_NEED     (WIHL_OFF + 1048576ull)           // ~163 MiB

typedef unsigned short u16;
typedef __attribute__((ext_vector_type(8))) short short8;
typedef __attribute__((ext_vector_type(4))) float f32x4;

__device__ __forceinline__ u16 f2bf(float f) {
  uint32_t u = __float_as_uint(f);
  u += 0x7fffu + ((u >> 16) & 1u);      // RNE
  return (u16)(u >> 16);
}
__device__ __forceinline__ float bf2f(u16 s) { return __uint_as_float(((uint32_t)s) << 16); }
__device__ __forceinline__ void splitf(float v, u16& h, u16& l) {
  h = f2bf(v);
  l = f2bf(v - bf2f(h));
}
__device__ __forceinline__ float sigm(float x) { return 1.f / (1.f + expf(-x)); }

// ---------------- prep: split x / conv_w(transposed) / w_ih into bf16 hi+lo ----------------
__global__ void prep_kernel(const float* __restrict__ x, const float* __restrict__ conv_w,
                            const float* __restrict__ w_ih,
                            u16* __restrict__ xh, u16* __restrict__ xl,
                            u16* __restrict__ wch, u16* __restrict__ wcl,
                            u16* __restrict__ wihh, u16* __restrict__ wihl) {
  int i = blockIdx.x * 256 + threadIdx.x;
  if (i < 4194304) {
    u16 h, l; splitf(x[i], h, l); xh[i] = h; xl[i] = l;
  } else if (i < 4194304 + 163840) {
    int j = i - 4194304;
    int f = j / 640, kk = j % 640;
    int c = kk & 127, k = kk >> 7;                 // kk = k*128 + c
    u16 h, l; splitf(conv_w[f * 640 + c * 5 + k], h, l);
    wch[f * 640 + kk] = h; wcl[f * 640 + kk] = l;
  } else if (i < 4194304 + 163840 + 524288) {
    int j = i - (4194304 + 163840);
    u16 h, l; splitf(w_ih[j], h, l); wihh[j] = h; wihl[j] = l;
  }
}

// ---------------- split-bf16 GEMM, 128x128 tile, BK=32, frag-order LDS ----------------
// MODE 0: conv  (K=640, B = windowed x, epilogue relu+BN -> xs hi/lo bf16 at [n][f])
// MODE 1: proj  (K=256, B = xs rows,    epilogue +bias   -> xp fp32 at [g][n])
template <int MODE>
__global__ __launch_bounds__(256, 1) void gemm_kernel(
    const u16* __restrict__ Ah, const u16* __restrict__ Al,
    const u16* __restrict__ Bh, const u16* __restrict__ Bl,
    const float* __restrict__ e0, const float* __restrict__ e1,
    const float* __restrict__ e2, const float* __restrict__ e3, const float* __restrict__ e4,
    u16* __restrict__ outh, u16* __restrict__ outl, float* __restrict__ outf) {
  const int KDIM = (MODE == 0) ? KC : 256;
  const int MT   = (MODE == 0) ? 2 : 16;
  int bx = blockIdx.x;
  int m0 = (bx % MT) * 128;
  int n0 = (bx / MT) * 128;
  __shared__ __attribute__((aligned(16))) u16 lds[4][4096]; // Ah Al Bh Bl, 512 entries x 8 bf16
  int t = threadIdx.x;
  int wave = t >> 6, lane = t & 63;
  int wm = wave & 1, wn = wave >> 1;

  f32x4 acc[4][4];
#pragma unroll
  for (int i = 0; i < 4; i++)
#pragma unroll
    for (int j = 0; j < 4; j++) acc[i][j] = (f32x4){0.f, 0.f, 0.f, 0.f};

  for (int k0 = 0; k0 < KDIM; k0 += 32) {
    __syncthreads();
    // stage: entries e: tile = e>>6 (0..7), l = e&63; lane layout matches MFMA frags
#pragma unroll
    for (int half = 0; half < 2; half++) {
      int e = half * 256 + t;
      int l = e & 63, tile = e >> 6;
      int kk = k0 + ((l >> 4) * 8);
      {
        int row = m0 + tile * 16 + (l & 15);
        const u16* sh = Ah + (long)row * KDIM + kk;
        const u16* sl = Al + (long)row * KDIM + kk;
        *(short8*)&lds[0][e * 8] = *(const short8*)sh;
        *(short8*)&lds[1][e * 8] = *(const short8*)sl;
      }
      {
        int n = n0 + tile * 16 + (l & 15);
        long base;
        if (MODE == 0) {
          int tp = n >> 5; if (tp > TLAST) tp = TLAST;   // clamp pad region
          base = (long)(n & 31) * 131072 + (long)tp * 256;
        } else {
          base = (long)n * 256;
        }
        *(short8*)&lds[2][e * 8] = *(const short8*)(Bh + base + kk);
        *(short8*)&lds[3][e * 8] = *(const short8*)(Bl + base + kk);
      }
    }
    __syncthreads();
    short8 af[4][2], bf[4][2];
#pragma unroll
    for (int i = 0; i < 4; i++) {
      af[i][0] = *(const short8*)&lds[0][((wm * 4 + i) * 64 + lane) * 8];
      af[i][1] = *(const short8*)&lds[1][((wm * 4 + i) * 64 + lane) * 8];
      bf[i][0] = *(const short8*)&lds[2][((wn * 4 + i) * 64 + lane) * 8];
      bf[i][1] = *(const short8*)&lds[3][((wn * 4 + i) * 64 + lane) * 8];
    }
#pragma unroll
    for (int am = 0; am < 4; am++)
#pragma unroll
      for (int an = 0; an < 4; an++) {
        acc[am][an] = __builtin_amdgcn_mfma_f32_16x16x32_bf16(af[am][0], bf[an][0], acc[am][an], 0, 0, 0);
        acc[am][an] = __builtin_amdgcn_mfma_f32_16x16x32_bf16(af[am][0], bf[an][1], acc[am][an], 0, 0, 0);
        acc[am][an] = __builtin_amdgcn_mfma_f32_16x16x32_bf16(af[am][1], bf[an][0], acc[am][an], 0, 0, 0);
      }
  }
  // epilogue: D element (row m, col n): m = (lane>>4)*4 + r within tile, n = lane&15
#pragma unroll
  for (int am = 0; am < 4; am++)
#pragma unroll
    for (int an = 0; an < 4; an++) {
      int n = n0 + (wn * 4 + an) * 16 + (lane & 15);
#pragma unroll
      for (int r = 0; r < 4; r++) {
        int m = m0 + (wm * 4 + am) * 16 + (lane >> 4) * 4 + r;
        float v = acc[am][an][r];
        if (MODE == 0) {
          float inv = e1[m] / sqrtf(e4[m] + 1e-5f);
          float sh  = e2[m] - e3[m] * inv;
          v = fmaxf(v + e0[m], 0.f) * inv + sh;
          u16 h, l; splitf(v, h, l);
          outh[(long)n * 256 + m] = h;
          outl[(long)n * 256 + m] = l;
        } else {
          v += e0[m] + e1[m];
          outf[(long)m * NPAD + n] = v;
        }
      }
    }
}

// ---------------- persistent skip-LSTM scan ----------------
// 64 wgs x 256 thr. wg owns hidden units j in [8*wg, 8*wg+8) -> 32 rows of W_hh
// (i,f,g,o) as pre-split MFMA A-frags in registers. h published per step as ONE
// packed u32/cell (hi<<16|lo) via relaxed AGENT-scope atomics (sc0 sc1 -> LLC
// coherence point, NO cache-maintenance fences). Ordering: __syncthreads()
// (drains vmcnt for all waves + compiler fence) sits between h-stores and the
// flag release, and between the flag poll and the h-loads.
__global__ __launch_bounds__(256, 1) void scan_kernel(
    const float* __restrict__ xp,     // [2048][NPAD]
    const float* __restrict__ w_hh,   // [2048][512]
    const float* __restrict__ w_uh,   // [512]
    const float* __restrict__ b_uh_p, // [1]
    uint32_t* __restrict__ hpk,       // [2][32][512] packed
    float* __restrict__ parts,        // [2][32][64]
    uint32_t* __restrict__ flags,     // [64][16] (64B stride)
    float* __restrict__ outp)         // [32][512]
{
  __shared__ float gl[32][33];
  __shared__ float u_l[32], ubin_l[32];
  __shared__ float wuh_l[8];
  int wg = blockIdx.x, t = threadIdx.x;
  int wave = t >> 6, lane = t & 63;
  int mt = wave & 1, nt = wave >> 1;

  if (t < 8)  wuh_l[t] = w_uh[wg * 8 + t];
  if (t < 32) { u_l[t] = 1.0f; ubin_l[t] = 1.0f; }

  // preload W_hh fragments (constant all steps): rows for this wave's M-tile
  int m = lane & 15, jj_w = m & 7;
  int q = mt * 2 + (m >> 3);                 // gate block 0..3 (i,f,g,o)
  long grow = (long)(q * 512 + wg * 8 + jj_w) * 512;
  short8 wfh[16], wfl[16];
#pragma unroll
  for (int ks = 0; ks < 16; ks++) {
    int kbase = ks * 32 + (lane >> 4) * 8;
    union { short8 v; u16 u[8]; } Uh, Ul;
#pragma unroll
    for (int i = 0; i < 8; i++) splitf(w_hh[grow + kbase + i], Uh.u[i], Ul.u[i]);
    wfh[ks] = Uh.v; wfl[ks] = Ul.v;
  }
  float bu = b_uh_p[0];

  // per-cell state in registers: cell (jj = t&7, b = t>>3)
  int pjj = t & 7, pb = t >> 3;
  float c_reg = 0.f, h_reg = 0.f;

  float xr[4];
#pragma unroll
  for (int qq = 0; qq < 4; qq++)
    xr[qq] = xp[(long)(qq * 512 + wg * 8 + pjj) * NPAD + pb];   // step 0
  __syncthreads();

  for (int s = 0; s < TP; s++) {
    int par = s & 1, np = par ^ 1;
    if (s > 0) {
      if (t < GWG) {
        while (__hip_atomic_load(&flags[t * 16], __ATOMIC_RELAXED, __HIP_MEMORY_SCOPE_AGENT) < (uint32_t)s)
          __builtin_amdgcn_s_sleep(1);
      }
      __syncthreads();   // compiler fence + all waves past poll
      if (t < 32) {      // u-update from step s-1 partials (identical in every wg)
        const float* pp = parts + par * 2048 + t * 64;
        float a = 0.f;
#pragma unroll
        for (int i = 0; i < 64; i++)
          a += __hip_atomic_load(pp + i, __ATOMIC_RELAXED, __HIP_MEMORY_SCOPE_AGENT);
        float du = sigm(a + bu);
        float up = u_l[t], ubp = ubin_l[t];
        float un = (ubp > 0.5f) ? du : (up + fminf(du, 1.f - up));
        u_l[t] = un; ubin_l[t] = rintf(un);
      }
    }
    // prefetch next step's xp slice (independent of recurrence) before MFMA chain
    float xr2[4] = {0.f, 0.f, 0.f, 0.f};
    if (s < TLAST) {
#pragma unroll
      for (int qq = 0; qq < 4; qq++)
        xr2[qq] = xp[(long)(qq * 512 + wg * 8 + pjj) * NPAD + (s + 1) * 32 + pb];
    }
    // MFMA: gates tile [16 rows x 16 batch]; B-frags from packed LLC-coherent h.
    // 3 independent accumulator chains (hi*hi, hi*lo, lo*hi).
    const uint32_t* bp = hpk + par * 16384 + (nt * 16 + (lane & 15)) * 512 + (lane >> 4) * 8;
    f32x4 a0 = (f32x4){0.f, 0.f, 0.f, 0.f};
    f32x4 a1 = a0, a2 = a0;
#pragma unroll
    for (int ks = 0; ks < 16; ks++) {
      uint32_t p[8];
#pragma unroll
      for (int i = 0; i < 8; i++)
        p[i] = __hip_atomic_load(bp + ks * 32 + i, __ATOMIC_RELAXED, __HIP_MEMORY_SCOPE_AGENT);
      union { uint32_t u[4]; short8 v; } Bh, Bl;
#pragma unroll
      for (int r = 0; r < 4; r++) {
        Bh.u[r] = __builtin_amdgcn_perm(p[2 * r + 1], p[2 * r], 0x07060302u);
        Bl.u[r] = __builtin_amdgcn_perm(p[2 * r + 1], p[2 * r], 0x05040100u);
      }
      a0 = __builtin_amdgcn_mfma_f32_16x16x32_bf16(wfh[ks], Bh.v, a0, 0, 0, 0);
      a1 = __builtin_amdgcn_mfma_f32_16x16x32_bf16(wfh[ks], Bl.v, a1, 0, 0, 0);
      a2 = __builtin_amdgcn_mfma_f32_16x16x32_bf16(wfl[ks], Bh.v, a2, 0, 0, 0);
    }
    f32x4 acc;
#pragma unroll
    for (int r = 0; r < 4; r++) acc[r] = (a0[r] + a1[r]) + a2[r];
    {
      int col = nt * 16 + (lane & 15);
      int rb = mt * 16 + (lane >> 4) * 4;
#pragma unroll
      for (int r = 0; r < 4; r++) gl[rb + r][col] = acc[r];
    }
    __syncthreads();
    // epilogue: one LSTM cell per thread
    {
      float gi = gl[pjj][pb]      + xr[0];
      float gf = gl[8 + pjj][pb]  + xr[1];
      float gg = gl[16 + pjj][pb] + xr[2];
      float go = gl[24 + pjj][pb] + xr[3];
      float ig = sigm(gi), fg = sigm(gf), og = sigm(go);
      float gt = tanhf(gg);
      float ct = fg * c_reg + ig * gt;
      float ht = og * tanhf(ct);
      bool upd = ubin_l[pb] > 0.5f;
      float cn = upd ? ct : c_reg;
      float hn = upd ? ht : h_reg;
      c_reg = cn; h_reg = hn;
      u16 hhi, hlo; splitf(hn, hhi, hlo);
      uint32_t pk = ((uint32_t)hhi << 16) | (uint32_t)hlo;
      __hip_atomic_store(&hpk[np * 16384 + pb * 512 + wg * 8 + pjj], pk,
                         __ATOMIC_RELAXED, __HIP_MEMORY_SCOPE_AGENT);
      float pr = cn * wuh_l[pjj];
      pr += __shfl_xor(pr, 1); pr += __shfl_xor(pr, 2); pr += __shfl_xor(pr, 4);
      if (pjj == 0)
        __hip_atomic_store(&parts[np * 2048 + pb * 64 + wg], pr,
                           __ATOMIC_RELAXED, __HIP_MEMORY_SCOPE_AGENT);
      if (s == TLAST) outp[pb * 512 + wg * 8 + pjj] = hn;
      xr[0] = xr2[0]; xr[1] = xr2[1]; xr[2] = xr2[2]; xr[3] = xr2[3];
    }
    __syncthreads();   // drains ALL waves' h/parts stores (vmcnt) + compiler fence
    if (t == 0) {
      __hip_atomic_store(&flags[wg * 16], (uint32_t)(s + 1),
                         __ATOMIC_RELEASE, __HIP_MEMORY_SCOPE_AGENT);
    }
  }
}

// ---------------- launcher ----------------
extern "C" void kernel_launch(void* const* d_in, const int* in_sizes, int n_in,
                              void* d_out, int out_size, void* d_ws, size_t ws_size,
                              hipStream_t stream) {
  const float* x      = (const float*)d_in[0];
  const float* conv_w = (const float*)d_in[1];
  const float* conv_b = (const float*)d_in[2];
  const float* gamma  = (const float*)d_in[3];
  const float* beta   = (const float*)d_in[4];
  const float* mean   = (const float*)d_in[5];
  const float* var    = (const float*)d_in[6];
  const float* w_ih   = (const float*)d_in[7];
  const float* w_hh   = (const float*)d_in[8];
  const float* b_ih   = (const float*)d_in[9];
  const float* b_hh   = (const float*)d_in[10];
  const float* w_uh   = (const float*)d_in[11];
  const float* b_uh   = (const float*)d_in[12];
  float* out = (float*)d_out;

  if (ws_size < WS_NEED) return;  // workspace too small: fail visibly via absmax

  char* w = (char*)d_ws;
  uint32_t* flags = (uint32_t*)(w + FLAGS_OFF);
  uint32_t* hpk   = (uint32_t*)(w + HPK_OFF);
  float* parts = (float*)(w + PARTS_OFF);
  float* xp    = (float*)(w + XP_OFF);
  u16*   xh    = (u16*)(w + XH_OFF);
  u16*   xl    = (u16*)(w + XL_OFF);
  u16*   xsh   = (u16*)(w + XSH_OFF);
  u16*   xsl   = (u16*)(w + XSL_OFF);
  u16*   wch   = (u16*)(w + WCH_OFF);
  u16*   wcl   = (u16*)(w + WCL_OFF);
  u16*   wihh  = (u16*)(w + WIHH_OFF);
  u16*   wihl  = (u16*)(w + WIHL_OFF);

  hipMemsetAsync(d_ws, 0, SYNC_BYTES, stream);  // flags + h0 + partials = 0

  prep_kernel<<<19072, 256, 0, stream>>>(x, conv_w, w_ih, xh, xl, wch, wcl, wihh, wihl);

  // conv GEMM: M=256(f) N=16384 K=640 -> xs (relu+BN, bf16 hi/lo, [n][f])
  gemm_kernel<0><<<2 * 128, 256, 0, stream>>>(wch, wcl, xh, xl,
                                              conv_b, gamma, beta, mean, var,
                                              xsh, xsl, nullptr);
  // proj GEMM: M=2048(g) N=16384 K=256 -> xp fp32 [g][n] (+ b_ih + b_hh)
  gemm_kernel<1><<<16 * 128, 256, 0, stream>>>(wihh, wihl, xsh, xsl,
                                               b_ih, b_hh, nullptr, nullptr, nullptr,
                                               nullptr, nullptr, xp);
  // persistent scan
  scan_kernel<<<GWG, 256, 0, stream>>>(xp, w_hh, w_uh, b_uh, hpk, parts, flags, out);
}

// Round 3
// 4888.796 us; speedup vs baseline: 1.9256x; 1.9256x over previous
//
#include <hip/hip_runtime.h>
#include <stdint.h>
#include <math.h>

// ---------------- problem constants ----------------
#define BB 32
#define TT 1024
#define CIN 128
#define FF 256
#define KW 5
#define HH 512
#define TP 510          // conv output length (VALID, stride 2)
#define TLAST 509
#define NPAD 16384      // padded (t',b) count (512*32)
#define KC 640          // conv GEMM K  (5*128)
#define GWG 256         // scan workgroups: 8 groups x 32 wgs
// group: 32 wgs, 4 batches, all 512 units; wg owns 16 units (64 gate rows)

// ---------------- workspace layout (bytes) ----------------
// sync region (memset to 0 every launch):
#define FLAGS_OFF   0u            // [8 grp][32 wg] flags, 64B stride = 16384
#define HST_OFF     16384u        // h streams: [8 grp][par2][hi/lo][4b][512] u16 = 131072
#define PARTS_OFF   147456u       // du partials: [8 grp][par2][4b][32 wg] f32 = 8192
#define SYNC_BYTES  155648u
// big buffers:
#define XP_OFF      155648ull                         // fp32 [8 grp][2048 g][512 t'][4 b] = 134217728
#define XH_OFF      (XP_OFF + 134217728ull)           // x hi bf16 [4194304]
#define XL_OFF      (XH_OFF + 8388608ull)
#define XSH_OFF     (XL_OFF + 8388608ull)             // xs hi bf16 [16384][256]
#define XSL_OFF     (XSH_OFF + 8388608ull)
#define WCH_OFF     (XSL_OFF + 8388608ull)            // conv W [256][640] hi
#define WCL_OFF     (WCH_OFF + 327680ull)
#define WIHH_OFF    (WCL_OFF + 327680ull)             // w_ih [2048][256] hi
#define WIHL_OFF    (WIHH_OFF + 1048576ull)
#define WS_NEED     (WIHL_OFF + 1048576ull)           // ~163 MiB

typedef unsigned short u16;
typedef unsigned long long u64;
typedef __attribute__((ext_vector_type(8))) short short8;
typedef __attribute__((ext_vector_type(4))) float f32x4;

__device__ __forceinline__ u16 f2bf(float f) {
  uint32_t u = __float_as_uint(f);
  u += 0x7fffu + ((u >> 16) & 1u);      // RNE
  return (u16)(u >> 16);
}
__device__ __forceinline__ float bf2f(u16 s) { return __uint_as_float(((uint32_t)s) << 16); }
__device__ __forceinline__ void splitf(float v, u16& h, u16& l) {
  h = f2bf(v);
  l = f2bf(v - bf2f(h));
}
__device__ __forceinline__ float sigm(float x) { return 1.f / (1.f + expf(-x)); }

// ---------------- prep: split x / conv_w(transposed) / w_ih into bf16 hi+lo ----------------
__global__ void prep_kernel(const float* __restrict__ x, const float* __restrict__ conv_w,
                            const float* __restrict__ w_ih,
                            u16* __restrict__ xh, u16* __restrict__ xl,
                            u16* __restrict__ wch, u16* __restrict__ wcl,
                            u16* __restrict__ wihh, u16* __restrict__ wihl) {
  int i = blockIdx.x * 256 + threadIdx.x;
  if (i < 4194304) {
    u16 h, l; splitf(x[i], h, l); xh[i] = h; xl[i] = l;
  } else if (i < 4194304 + 163840) {
    int j = i - 4194304;
    int f = j / 640, kk = j % 640;
    int c = kk & 127, k = kk >> 7;                 // kk = k*128 + c
    u16 h, l; splitf(conv_w[f * 640 + c * 5 + k], h, l);
    wch[f * 640 + kk] = h; wcl[f * 640 + kk] = l;
  } else if (i < 4194304 + 163840 + 524288) {
    int j = i - (4194304 + 163840);
    u16 h, l; splitf(w_ih[j], h, l); wihh[j] = h; wihl[j] = l;
  }
}

// ---------------- split-bf16 GEMM, 128x128 tile, BK=32, frag-order LDS ----------------
// MODE 0: conv  (K=640, B = windowed x, epilogue relu+BN -> xs hi/lo bf16 at [n][f])
// MODE 1: proj  (K=256, B = xs rows,    epilogue +bias   -> xp fp32 at [grp][g][t'][4b])
template <int MODE>
__global__ __launch_bounds__(256, 1) void gemm_kernel(
    const u16* __restrict__ Ah, const u16* __restrict__ Al,
    const u16* __restrict__ Bh, const u16* __restrict__ Bl,
    const float* __restrict__ e0, const float* __restrict__ e1,
    const float* __restrict__ e2, const float* __restrict__ e3, const float* __restrict__ e4,
    u16* __restrict__ outh, u16* __restrict__ outl, float* __restrict__ outf) {
  const int KDIM = (MODE == 0) ? KC : 256;
  const int MT   = (MODE == 0) ? 2 : 16;
  int bx = blockIdx.x;
  int m0 = (bx % MT) * 128;
  int n0 = (bx / MT) * 128;
  __shared__ __attribute__((aligned(16))) u16 lds[4][4096]; // Ah Al Bh Bl, 512 entries x 8 bf16
  int t = threadIdx.x;
  int wave = t >> 6, lane = t & 63;
  int wm = wave & 1, wn = wave >> 1;

  f32x4 acc[4][4];
#pragma unroll
  for (int i = 0; i < 4; i++)
#pragma unroll
    for (int j = 0; j < 4; j++) acc[i][j] = (f32x4){0.f, 0.f, 0.f, 0.f};

  for (int k0 = 0; k0 < KDIM; k0 += 32) {
    __syncthreads();
#pragma unroll
    for (int half = 0; half < 2; half++) {
      int e = half * 256 + t;
      int l = e & 63, tile = e >> 6;
      int kk = k0 + ((l >> 4) * 8);
      {
        int row = m0 + tile * 16 + (l & 15);
        const u16* sh = Ah + (long)row * KDIM + kk;
        const u16* sl = Al + (long)row * KDIM + kk;
        *(short8*)&lds[0][e * 8] = *(const short8*)sh;
        *(short8*)&lds[1][e * 8] = *(const short8*)sl;
      }
      {
        int n = n0 + tile * 16 + (l & 15);
        long base;
        if (MODE == 0) {
          int tp = n >> 5; if (tp > TLAST) tp = TLAST;   // clamp pad region
          base = (long)(n & 31) * 131072 + (long)tp * 256;
        } else {
          base = (long)n * 256;
        }
        *(short8*)&lds[2][e * 8] = *(const short8*)(Bh + base + kk);
        *(short8*)&lds[3][e * 8] = *(const short8*)(Bl + base + kk);
      }
    }
    __syncthreads();
    short8 af[4][2], bf[4][2];
#pragma unroll
    for (int i = 0; i < 4; i++) {
      af[i][0] = *(const short8*)&lds[0][((wm * 4 + i) * 64 + lane) * 8];
      af[i][1] = *(const short8*)&lds[1][((wm * 4 + i) * 64 + lane) * 8];
      bf[i][0] = *(const short8*)&lds[2][((wn * 4 + i) * 64 + lane) * 8];
      bf[i][1] = *(const short8*)&lds[3][((wn * 4 + i) * 64 + lane) * 8];
    }
#pragma unroll
    for (int am = 0; am < 4; am++)
#pragma unroll
      for (int an = 0; an < 4; an++) {
        acc[am][an] = __builtin_amdgcn_mfma_f32_16x16x32_bf16(af[am][0], bf[an][0], acc[am][an], 0, 0, 0);
        acc[am][an] = __builtin_amdgcn_mfma_f32_16x16x32_bf16(af[am][0], bf[an][1], acc[am][an], 0, 0, 0);
        acc[am][an] = __builtin_amdgcn_mfma_f32_16x16x32_bf16(af[am][1], bf[an][0], acc[am][an], 0, 0, 0);
      }
  }
  // epilogue: D element (row m, col n): m = (lane>>4)*4 + r within tile, n = lane&15
#pragma unroll
  for (int am = 0; am < 4; am++)
#pragma unroll
    for (int an = 0; an < 4; an++) {
      int n = n0 + (wn * 4 + an) * 16 + (lane & 15);
#pragma unroll
      for (int r = 0; r < 4; r++) {
        int m = m0 + (wm * 4 + am) * 16 + (lane >> 4) * 4 + r;
        float v = acc[am][an][r];
        if (MODE == 0) {
          float inv = e1[m] / sqrtf(e4[m] + 1e-5f);
          float sh  = e2[m] - e3[m] * inv;
          v = fmaxf(v + e0[m], 0.f) * inv + sh;
          u16 h, l; splitf(v, h, l);
          outh[(long)n * 256 + m] = h;
          outl[(long)n * 256 + m] = l;
        } else {
          v += e0[m] + e1[m];
          int tp = n >> 5, b = n & 31;
          int grp = b >> 2, bb = b & 3;
          // [grp][g=m][t'][4b] floats
          outf[(long)grp * 4194304 + (long)m * 2048 + tp * 4 + bb] = v;
        }
      }
    }
}

// ---------------- persistent skip-LSTM scan ----------------
// 8 independent groups x 32 wgs. Group g handles batches [4g,4g+4), all 512 units.
// wg owns 16 units (64 gate rows); W_hh pre-split in registers (128 VGPR/lane).
// h exchanged per step as separate hi/lo bf16 streams via relaxed AGENT-scope
// u64 atomics (sc0 sc1 -> LLC coherence point). NO cache-maintenance fences:
// ordering = data stores -> __syncthreads (vmcnt drain, all waves) -> relaxed
// flag store; consumer: flag poll -> __syncthreads -> data loads (LLC-direct).
__global__ __launch_bounds__(256, 2) void scan_kernel(
    const float* __restrict__ xpg,    // [8][2048][512][4]
    const float* __restrict__ w_hh,   // [2048][512]
    const float* __restrict__ w_uh,   // [512]
    const float* __restrict__ b_uh_p, // [1]
    u16* __restrict__ hst,            // streams, see HST_OFF layout
    float* __restrict__ parts,        // [8][2][4][32]
    uint32_t* __restrict__ flags,     // [8][32][16] (64B stride)
    float* __restrict__ outp)         // [32][512]
{
  __shared__ float gl[4][16][6];      // [gate][unit][batch(+pad)]
  __shared__ float u_l[4], ubin_l[4];
  __shared__ float wuh_l[16];
  int group = blockIdx.x >> 5, slot = blockIdx.x & 31;
  int t = threadIdx.x;
  int wave = t >> 6, lane = t & 63;

  if (t < 16) wuh_l[t] = w_uh[slot * 16 + t];
  if (t < 4)  { u_l[t] = 1.0f; ubin_l[t] = 1.0f; }

  // ---- preload W_hh fragments: wave handles gate q=wave, units 0..15 of this wg
  int um = lane & 15, kq = lane >> 4;
  long wrow = (long)(wave * 512 + slot * 16 + um) * 512;
  short8 wfh[16], wfl[16];
#pragma unroll
  for (int ks = 0; ks < 16; ks++) {
    union { short8 v; u16 u[8]; } Uh, Ul;
#pragma unroll
    for (int i = 0; i < 8; i++) splitf(w_hh[wrow + ks * 32 + kq * 8 + i], Uh.u[i], Ul.u[i]);
    wfh[ks] = Uh.v; wfl[ks] = Ul.v;
  }
  float bu = b_uh_p[0];

  // cell state: thread t<64 owns (unit jj = t>>2, batch bb = t&3)
  int jj = t >> 2, bbt = t & 3;
  float c_reg = 0.f, h_reg = 0.f;

  // h stream bases (u16 index), group-local
  // layout: group*8192 + par*4096 + which*2048 + b*512 + u
  int nb = lane & 3;
  long hbase_rd = (long)group * 8192 + nb * 512 + kq * 8;   // + par*4096 (+2048 for lo)
  long hbase_wr = (long)group * 8192 + bbt * 512 + slot * 16 + jj;  // u16 idx (jj even for store)

  uint32_t* myflag = flags + ((long)group * 32 + slot) * 16;

  __syncthreads();

  for (int s = 0; s < TP; s++) {
    int par = s & 1, np = par ^ 1;
    // xp gate inputs: plain cached float4 per gate (component bbt); issue early
    f32x4 xq[4];
    if (t < 64) {
#pragma unroll
      for (int q = 0; q < 4; q++)
        xq[q] = *(const f32x4*)(xpg + (long)group * 4194304 +
                                ((long)(q * 512 + slot * 16 + jj)) * 2048 + s * 4);
    }
    if (s > 0) {
      if (t < 32) {
        const uint32_t* fp = flags + ((long)group * 32 + t) * 16;
        while (__hip_atomic_load(fp, __ATOMIC_RELAXED, __HIP_MEMORY_SCOPE_AGENT) < (uint32_t)s)
          __builtin_amdgcn_s_sleep(1);
      }
      __syncthreads();   // all waves past poll; compiler fence
      if (t < 4) {       // u-update from step s-1 partials (identical in all 32 wgs: fixed order)
        const float* pp = parts + (long)group * 256 + par * 128 + t * 32;
        float a = 0.f;
#pragma unroll
        for (int i = 0; i < 32; i++)
          a += __hip_atomic_load(pp + i, __ATOMIC_RELAXED, __HIP_MEMORY_SCOPE_AGENT);
        float du = sigm(a + bu);
        float up = u_l[t], ubp = ubin_l[t];
        float un = (ubp > 0.5f) ? du : (up + fminf(du, 1.f - up));
        u_l[t] = un; ubin_l[t] = rintf(un);
      }
    }
    // ---- B-frag loads (u64 relaxed agent atomics -> dwordx2 sc0 sc1), 2 chunks of 8 ks
    const u64* hi_p = (const u64*)hst + ((hbase_rd + par * 4096) >> 2);
    const u64* lo_p = hi_p + (2048 >> 2);
    f32x4 a0 = (f32x4){0.f, 0.f, 0.f, 0.f};
    f32x4 a1 = a0, a2 = a0;
#pragma unroll
    for (int ch = 0; ch < 2; ch++) {
      union { u64 a[2]; short8 v; } Bh[8], Bl[8];
#pragma unroll
      for (int k = 0; k < 8; k++) {
        int ks = ch * 8 + k;
        Bh[k].a[0] = __hip_atomic_load(hi_p + ks * 8,     __ATOMIC_RELAXED, __HIP_MEMORY_SCOPE_AGENT);
        Bh[k].a[1] = __hip_atomic_load(hi_p + ks * 8 + 1, __ATOMIC_RELAXED, __HIP_MEMORY_SCOPE_AGENT);
        Bl[k].a[0] = __hip_atomic_load(lo_p + ks * 8,     __ATOMIC_RELAXED, __HIP_MEMORY_SCOPE_AGENT);
        Bl[k].a[1] = __hip_atomic_load(lo_p + ks * 8 + 1, __ATOMIC_RELAXED, __HIP_MEMORY_SCOPE_AGENT);
      }
#pragma unroll
      for (int k = 0; k < 8; k++) {
        int ks = ch * 8 + k;
        a0 = __builtin_amdgcn_mfma_f32_16x16x32_bf16(wfh[ks], Bh[k].v, a0, 0, 0, 0);
        a1 = __builtin_amdgcn_mfma_f32_16x16x32_bf16(wfh[ks], Bl[k].v, a1, 0, 0, 0);
        a2 = __builtin_amdgcn_mfma_f32_16x16x32_bf16(wfl[ks], Bh[k].v, a2, 0, 0, 0);
      }
    }
    // write gates tile: D row = (lane>>4)*4+r = unit, col = lane&15 = batch (real < 4)
    {
      int col = lane & 15;
      if (col < 4) {
        f32x4 acc;
#pragma unroll
        for (int r = 0; r < 4; r++) acc[r] = (a0[r] + a1[r]) + a2[r];
#pragma unroll
        for (int r = 0; r < 4; r++) gl[wave][kq * 4 + r][col] = acc[r];
      }
    }
    __syncthreads();
    // ---- epilogue: one LSTM cell per thread (wave 0 only)
    if (t < 64) {
      float gi = gl[0][jj][bbt] + xq[0][bbt];
      float gf = gl[1][jj][bbt] + xq[1][bbt];
      float gg = gl[2][jj][bbt] + xq[2][bbt];
      float go = gl[3][jj][bbt] + xq[3][bbt];
      float ig = sigm(gi), fg = sigm(gf), og = sigm(go);
      float gt = tanhf(gg);
      float ct = fg * c_reg + ig * gt;
      float ht = og * tanhf(ct);
      bool upd = ubin_l[bbt] > 0.5f;
      float cn = upd ? ct : c_reg;
      float hn = upd ? ht : h_reg;
      c_reg = cn; h_reg = hn;
      u16 hhi, hlo; splitf(hn, hhi, hlo);
      // pack unit pairs (jj, jj^1) into u32; lanes t and t^4 hold the pair
      uint32_t hi32 = (uint32_t)hhi, lo32 = (uint32_t)hlo;
      uint32_t hi_o = __shfl_xor(hi32, 4), lo_o = __shfl_xor(lo32, 4);
      if ((jj & 1) == 0) {
        uint32_t wh = hi32 | (hi_o << 16);
        uint32_t wl = lo32 | (lo_o << 16);
        long u32idx = (hbase_wr + (long)np * 4096) >> 1;          // hi stream
        uint32_t* hp = (uint32_t*)hst;
        __hip_atomic_store(hp + u32idx, wh, __ATOMIC_RELAXED, __HIP_MEMORY_SCOPE_AGENT);
        __hip_atomic_store(hp + u32idx + (2048 >> 1), wl, __ATOMIC_RELAXED, __HIP_MEMORY_SCOPE_AGENT);
      }
      // du partial: sum over this wg's 16 units per batch (lanes t == bbt mod 4)
      float pr = cn * wuh_l[jj];
      pr += __shfl_xor(pr, 4); pr += __shfl_xor(pr, 8);
      pr += __shfl_xor(pr, 16); pr += __shfl_xor(pr, 32);
      if (t < 4)
        __hip_atomic_store(parts + (long)group * 256 + np * 128 + t * 32 + slot, pr,
                           __ATOMIC_RELAXED, __HIP_MEMORY_SCOPE_AGENT);
      if (s == TLAST) outp[(long)(group * 4 + bbt) * 512 + slot * 16 + jj] = hn;
    }
    __syncthreads();   // drains ALL waves' stores (vmcnt(0)) + barrier
    if (t == 0)
      __hip_atomic_store(myflag, (uint32_t)(s + 1), __ATOMIC_RELAXED, __HIP_MEMORY_SCOPE_AGENT);
  }
}

// ---------------- launcher ----------------
extern "C" void kernel_launch(void* const* d_in, const int* in_sizes, int n_in,
                              void* d_out, int out_size, void* d_ws, size_t ws_size,
                              hipStream_t stream) {
  const float* x      = (const float*)d_in[0];
  const float* conv_w = (const float*)d_in[1];
  const float* conv_b = (const float*)d_in[2];
  const float* gamma  = (const float*)d_in[3];
  const float* beta   = (const float*)d_in[4];
  const float* mean   = (const float*)d_in[5];
  const float* var    = (const float*)d_in[6];
  const float* w_ih   = (const float*)d_in[7];
  const float* w_hh   = (const float*)d_in[8];
  const float* b_ih   = (const float*)d_in[9];
  const float* b_hh   = (const float*)d_in[10];
  const float* w_uh   = (const float*)d_in[11];
  const float* b_uh   = (const float*)d_in[12];
  float* out = (float*)d_out;

  if (ws_size < WS_NEED) return;  // workspace too small: fail visibly via absmax

  char* w = (char*)d_ws;
  uint32_t* flags = (uint32_t*)(w + FLAGS_OFF);
  u16*   hst   = (u16*)(w + HST_OFF);
  float* parts = (float*)(w + PARTS_OFF);
  float* xp    = (float*)(w + XP_OFF);
  u16*   xh    = (u16*)(w + XH_OFF);
  u16*   xl    = (u16*)(w + XL_OFF);
  u16*   xsh   = (u16*)(w + XSH_OFF);
  u16*   xsl   = (u16*)(w + XSL_OFF);
  u16*   wch   = (u16*)(w + WCH_OFF);
  u16*   wcl   = (u16*)(w + WCL_OFF);
  u16*   wihh  = (u16*)(w + WIHH_OFF);
  u16*   wihl  = (u16*)(w + WIHL_OFF);

  hipMemsetAsync(d_ws, 0, SYNC_BYTES, stream);  // flags + h0 + partials = 0

  prep_kernel<<<19072, 256, 0, stream>>>(x, conv_w, w_ih, xh, xl, wch, wcl, wihh, wihl);

  // conv GEMM: M=256(f) N=16384 K=640 -> xs (relu+BN, bf16 hi/lo, [n][f])
  gemm_kernel<0><<<2 * 128, 256, 0, stream>>>(wch, wcl, xh, xl,
                                              conv_b, gamma, beta, mean, var,
                                              xsh, xsl, nullptr);
  // proj GEMM: M=2048(g) N=16384 K=256 -> xp fp32 [grp][g][t'][4b] (+ b_ih + b_hh)
  gemm_kernel<1><<<16 * 128, 256, 0, stream>>>(wihh, wihl, xsh, xsl,
                                               b_ih, b_hh, nullptr, nullptr, nullptr,
                                               nullptr, nullptr, xp);
  // persistent scan: 8 groups x 32 wgs
  scan_kernel<<<GWG, 256, 0, stream>>>(xp, w_hh, w_uh, b_uh, hst, parts, flags, out);
}

// Round 4
// 2824.901 us; speedup vs baseline: 3.3324x; 1.7306x over previous
//
#include <hip/hip_runtime.h>
#include <stdint.h>
#include <math.h>

// ---------------- problem constants ----------------
#define BB 32
#define TT 1024
#define CIN 128
#define FF 256
#define KW 5
#define HH 512
#define TP 510          // conv output length (VALID, stride 2)
#define TLAST 509
#define NPAD 16384      // padded (t',b) count (512*32)
#define KC 640          // conv GEMM K  (5*128)
#define GWG 256         // scan workgroups: 8 groups x 32 wgs

// ---------------- workspace layout (bytes) ----------------
// sync region (memset to 0 every launch): tagged words, tag0 never matches (want>=1)
#define HTAG_OFF    0u            // h words: [8 grp][par2][4b][512u] u64 = 262144
#define PTAG_OFF    262144u       // parts:   [8 grp][par2][4b][32wg] u64 = 16384
#define SYNC_BYTES  278528u
// big buffers:
#define XP_OFF      278528ull                         // fp32 [8 grp][2048 g][512 t'][4 b] = 134217728
#define XH_OFF      (XP_OFF + 134217728ull)           // x hi bf16 [4194304]
#define XL_OFF      (XH_OFF + 8388608ull)
#define XSH_OFF     (XL_OFF + 8388608ull)             // xs hi bf16 [16384][256]
#define XSL_OFF     (XSH_OFF + 8388608ull)
#define WCH_OFF     (XSL_OFF + 8388608ull)            // conv W [256][640] hi
#define WCL_OFF     (WCH_OFF + 327680ull)
#define WIHH_OFF    (WCL_OFF + 327680ull)             // w_ih [2048][256] hi
#define WIHL_OFF    (WIHH_OFF + 1048576ull)
#define WS_NEED     (WIHL_OFF + 1048576ull)           // ~163.5 MiB

typedef unsigned short u16;
typedef unsigned long long u64;
typedef __attribute__((ext_vector_type(8))) short short8;
typedef __attribute__((ext_vector_type(4))) float f32x4;
typedef __attribute__((ext_vector_type(4))) unsigned int u32x4;

__device__ __forceinline__ u16 f2bf(float f) {
  uint32_t u = __float_as_uint(f);
  u += 0x7fffu + ((u >> 16) & 1u);      // RNE
  return (u16)(u >> 16);
}
__device__ __forceinline__ float bf2f(u16 s) { return __uint_as_float(((uint32_t)s) << 16); }
__device__ __forceinline__ void splitf(float v, u16& h, u16& l) {
  h = f2bf(v);
  l = f2bf(v - bf2f(h));
}
__device__ __forceinline__ float sigm(float x) { return 1.f / (1.f + expf(-x)); }

// ---------------- prep: split x / conv_w(transposed) / w_ih into bf16 hi+lo ----------------
__global__ void prep_kernel(const float* __restrict__ x, const float* __restrict__ conv_w,
                            const float* __restrict__ w_ih,
                            u16* __restrict__ xh, u16* __restrict__ xl,
                            u16* __restrict__ wch, u16* __restrict__ wcl,
                            u16* __restrict__ wihh, u16* __restrict__ wihl) {
  int i = blockIdx.x * 256 + threadIdx.x;
  if (i < 4194304) {
    u16 h, l; splitf(x[i], h, l); xh[i] = h; xl[i] = l;
  } else if (i < 4194304 + 163840) {
    int j = i - 4194304;
    int f = j / 640, kk = j % 640;
    int c = kk & 127, k = kk >> 7;                 // kk = k*128 + c
    u16 h, l; splitf(conv_w[f * 640 + c * 5 + k], h, l);
    wch[f * 640 + kk] = h; wcl[f * 640 + kk] = l;
  } else if (i < 4194304 + 163840 + 524288) {
    int j = i - (4194304 + 163840);
    u16 h, l; splitf(w_ih[j], h, l); wihh[j] = h; wihl[j] = l;
  }
}

// ---------------- split-bf16 GEMM, 128x128 tile, BK=32, frag-order LDS ----------------
// MODE 0: conv  (K=640, B = windowed x, epilogue relu+BN -> xs hi/lo bf16 at [n][f])
// MODE 1: proj  (K=256, B = xs rows,    epilogue +bias   -> xp fp32 at [grp][g][t'][4b])
template <int MODE>
__global__ __launch_bounds__(256, 1) void gemm_kernel(
    const u16* __restrict__ Ah, const u16* __restrict__ Al,
    const u16* __restrict__ Bh, const u16* __restrict__ Bl,
    const float* __restrict__ e0, const float* __restrict__ e1,
    const float* __restrict__ e2, const float* __restrict__ e3, const float* __restrict__ e4,
    u16* __restrict__ outh, u16* __restrict__ outl, float* __restrict__ outf) {
  const int KDIM = (MODE == 0) ? KC : 256;
  const int MT   = (MODE == 0) ? 2 : 16;
  int bx = blockIdx.x;
  int m0 = (bx % MT) * 128;
  int n0 = (bx / MT) * 128;
  __shared__ __attribute__((aligned(16))) u16 lds[4][4096]; // Ah Al Bh Bl, 512 entries x 8 bf16
  int t = threadIdx.x;
  int wave = t >> 6, lane = t & 63;
  int wm = wave & 1, wn = wave >> 1;

  f32x4 acc[4][4];
#pragma unroll
  for (int i = 0; i < 4; i++)
#pragma unroll
    for (int j = 0; j < 4; j++) acc[i][j] = (f32x4){0.f, 0.f, 0.f, 0.f};

  for (int k0 = 0; k0 < KDIM; k0 += 32) {
    __syncthreads();
#pragma unroll
    for (int half = 0; half < 2; half++) {
      int e = half * 256 + t;
      int l = e & 63, tile = e >> 6;
      int kk = k0 + ((l >> 4) * 8);
      {
        int row = m0 + tile * 16 + (l & 15);
        const u16* sh = Ah + (long)row * KDIM + kk;
        const u16* sl = Al + (long)row * KDIM + kk;
        *(short8*)&lds[0][e * 8] = *(const short8*)sh;
        *(short8*)&lds[1][e * 8] = *(const short8*)sl;
      }
      {
        int n = n0 + tile * 16 + (l & 15);
        long base;
        if (MODE == 0) {
          int tp = n >> 5; if (tp > TLAST) tp = TLAST;   // clamp pad region
          base = (long)(n & 31) * 131072 + (long)tp * 256;
        } else {
          base = (long)n * 256;
        }
        *(short8*)&lds[2][e * 8] = *(const short8*)(Bh + base + kk);
        *(short8*)&lds[3][e * 8] = *(const short8*)(Bl + base + kk);
      }
    }
    __syncthreads();
    short8 af[4][2], bf[4][2];
#pragma unroll
    for (int i = 0; i < 4; i++) {
      af[i][0] = *(const short8*)&lds[0][((wm * 4 + i) * 64 + lane) * 8];
      af[i][1] = *(const short8*)&lds[1][((wm * 4 + i) * 64 + lane) * 8];
      bf[i][0] = *(const short8*)&lds[2][((wn * 4 + i) * 64 + lane) * 8];
      bf[i][1] = *(const short8*)&lds[3][((wn * 4 + i) * 64 + lane) * 8];
    }
#pragma unroll
    for (int am = 0; am < 4; am++)
#pragma unroll
      for (int an = 0; an < 4; an++) {
        acc[am][an] = __builtin_amdgcn_mfma_f32_16x16x32_bf16(af[am][0], bf[an][0], acc[am][an], 0, 0, 0);
        acc[am][an] = __builtin_amdgcn_mfma_f32_16x16x32_bf16(af[am][0], bf[an][1], acc[am][an], 0, 0, 0);
        acc[am][an] = __builtin_amdgcn_mfma_f32_16x16x32_bf16(af[am][1], bf[an][0], acc[am][an], 0, 0, 0);
      }
  }
  // epilogue: D element (row m, col n): m = (lane>>4)*4 + r within tile, n = lane&15
#pragma unroll
  for (int am = 0; am < 4; am++)
#pragma unroll
    for (int an = 0; an < 4; an++) {
      int n = n0 + (wn * 4 + an) * 16 + (lane & 15);
#pragma unroll
      for (int r = 0; r < 4; r++) {
        int m = m0 + (wm * 4 + am) * 16 + (lane >> 4) * 4 + r;
        float v = acc[am][an][r];
        if (MODE == 0) {
          float inv = e1[m] / sqrtf(e4[m] + 1e-5f);
          float sh  = e2[m] - e3[m] * inv;
          v = fmaxf(v + e0[m], 0.f) * inv + sh;
          u16 h, l; splitf(v, h, l);
          outh[(long)n * 256 + m] = h;
          outl[(long)n * 256 + m] = l;
        } else {
          v += e0[m] + e1[m];
          int tp = n >> 5, b = n & 31;
          int grp = b >> 2, bb = b & 3;
          // [grp][g=m][t'][4b] floats
          outf[(long)grp * 4194304 + (long)m * 2048 + tp * 4 + bb] = v;
        }
      }
    }
}

// ---------------- persistent skip-LSTM scan (tag-in-data protocol) ----------------
// 8 independent groups x 32 wgs. Group = blockIdx>>5, batches [4g,4g+4), all 512 units.
// wg owns 16 units (64 gate rows). Waves split K: wave w does K[128w,128w+128) for all
// 4 gates; partial gate sums reduced via LDS. Every shared word is u64
// (tag<<32 | payload) stored/loaded with ONE relaxed agent-scope dwordx2 -> no flags,
// no producer-side drain, no fences. Consumer polls data tags directly.
// Overwrite safety: producer past step s read all tag-s words => all wgs stored tag-s
// => all wgs finished reading the tag-(s-1) data being overwritten.
__global__ __launch_bounds__(256, 1) void scan_kernel(
    const float* __restrict__ xpg,    // [8][2048][512][4]
    const float* __restrict__ w_hh,   // [2048][512]
    const float* __restrict__ w_uh,   // [512]
    const float* __restrict__ b_uh_p, // [1]
    u64* __restrict__ htag,           // [8][2][4][512]
    u64* __restrict__ ptag,           // [8][2][4][32]
    float* __restrict__ outp)         // [32][512]
{
  __shared__ __attribute__((aligned(16))) u16 sh_hi[2048];  // [4b][512u]
  __shared__ __attribute__((aligned(16))) u16 sh_lo[2048];
  __shared__ float gpart[4][4][16][4];  // [wave][gate][unit][batch]
  __shared__ float sparts[4][32];
  __shared__ float u_l[4], ubin_l[4];
  __shared__ float wuh_l[16];
  int group = blockIdx.x >> 5, slot = blockIdx.x & 31;
  int t = threadIdx.x;
  int wave = t >> 6, lane = t & 63;
  int um = lane & 15, kq = lane >> 4;
  int nbc = um & 3;

  if (t < 16) wuh_l[t] = w_uh[slot * 16 + t];
  if (t < 4)  { u_l[t] = 1.0f; ubin_l[t] = 1.0f; }

  // ---- preload W_hh fragments: wave w covers K[128w..128w+128) for gates 0..3
  short8 wfh[4][4], wfl[4][4];
#pragma unroll
  for (int q = 0; q < 4; q++) {
    long row = (long)(q * 512 + slot * 16 + um) * 512;
#pragma unroll
    for (int k4 = 0; k4 < 4; k4++) {
      union { short8 v; u16 u[8]; } Uh, Ul;
      long col0 = wave * 128 + k4 * 32 + kq * 8;
#pragma unroll
      for (int i = 0; i < 8; i++) splitf(w_hh[row + col0 + i], Uh.u[i], Ul.u[i]);
      wfh[q][k4] = Uh.v; wfl[q][k4] = Ul.v;
    }
  }
  float bu = b_uh_p[0];

  // cell state: thread t<64 owns (unit jj = t>>2, batch bb = t&3)
  int jj = t >> 2, bbt = t & 3;
  float c_reg = 0.f, h_reg = 0.f;

  const u64* hrd  = htag + (long)group * 4096 + t * 8;   // + par*2048
  u64* hwr        = htag + (long)group * 4096 + bbt * 512 + slot * 16 + jj;  // + np*2048
  const u64* prd  = ptag + (long)group * 256 + (t - 128); // + par*128 (t>=128)
  u64* pwr        = ptag + (long)group * 256 + bbt * 32 + slot;              // + np*128

  __syncthreads();

  for (int s = 0; s < TP; s++) {
    int par = s & 1, np = par ^ 1;
    // xp gate inputs (plain cached loads), issued before polls
    f32x4 xq[4];
    if (t < 64) {
#pragma unroll
      for (int q = 0; q < 4; q++)
        xq[q] = *(const f32x4*)(xpg + (long)group * 4194304 +
                                ((long)(q * 512 + slot * 16 + jj)) * 2048 + s * 4);
    }
    // ---- stage h (all 256 threads, 8 tagged words each -> one 64B line/thread)
    if (s == 0) {
      *(u32x4*)((char*)sh_hi + t * 16) = (u32x4){0u, 0u, 0u, 0u};
      *(u32x4*)((char*)sh_lo + t * 16) = (u32x4){0u, 0u, 0u, 0u};
    } else {
      const u64* hp = hrd + (long)par * 2048;
      u64 v[8];
      bool ok;
      do {
        ok = true;
#pragma unroll
        for (int i = 0; i < 8; i++) {
          v[i] = __hip_atomic_load(hp + i, __ATOMIC_RELAXED, __HIP_MEMORY_SCOPE_AGENT);
          ok = ok && ((uint32_t)(v[i] >> 32) == (uint32_t)s);
        }
      } while (!ok);
      u32x4 hv, lv;
#pragma unroll
      for (int r = 0; r < 4; r++) {
        uint32_t p0 = (uint32_t)v[2 * r], p1 = (uint32_t)v[2 * r + 1];
        hv[r] = __builtin_amdgcn_perm(p1, p0, 0x07060302u);
        lv[r] = __builtin_amdgcn_perm(p1, p0, 0x05040100u);
      }
      *(u32x4*)((char*)sh_hi + t * 16) = hv;
      *(u32x4*)((char*)sh_lo + t * 16) = lv;
      // ---- stage parts (threads 128..255, one tagged word each)
      if (t >= 128) {
        const u64* pp = prd + (long)par * 128;
        u64 w;
        do {
          w = __hip_atomic_load(pp, __ATOMIC_RELAXED, __HIP_MEMORY_SCOPE_AGENT);
        } while ((uint32_t)(w >> 32) != (uint32_t)s);
        int idx = t - 128;
        sparts[idx >> 5][idx & 31] = __uint_as_float((uint32_t)w);
      }
    }
    __syncthreads();   // stage visible to all; also orders vs prev epilogue reads
    // ---- u-update (t<4), reads staged parts; identical fixed order in all 32 wgs
    if (s > 0 && t < 4) {
      float a = 0.f;
#pragma unroll
      for (int i = 0; i < 32; i++) a += sparts[t][i];
      float du = sigm(a + bu);
      float up = u_l[t], ubp = ubin_l[t];
      float un = (ubp > 0.5f) ? du : (up + fminf(du, 1.f - up));
      u_l[t] = un; ubin_l[t] = rintf(un);
    }
    // ---- MFMA: wave w does its K-quarter for all 4 gates (12 indep acc chains)
    f32x4 A0[4], A1[4], A2[4];
#pragma unroll
    for (int q = 0; q < 4; q++) {
      A0[q] = (f32x4){0.f, 0.f, 0.f, 0.f}; A1[q] = A0[q]; A2[q] = A0[q];
    }
#pragma unroll
    for (int k4 = 0; k4 < 4; k4++) {
      int ko = (wave * 4 + k4) * 32 + kq * 8;
      short8 bh = *(const short8*)&sh_hi[nbc * 512 + ko];
      short8 bl = *(const short8*)&sh_lo[nbc * 512 + ko];
#pragma unroll
      for (int q = 0; q < 4; q++) {
        A0[q] = __builtin_amdgcn_mfma_f32_16x16x32_bf16(wfh[q][k4], bh, A0[q], 0, 0, 0);
        A1[q] = __builtin_amdgcn_mfma_f32_16x16x32_bf16(wfh[q][k4], bl, A1[q], 0, 0, 0);
        A2[q] = __builtin_amdgcn_mfma_f32_16x16x32_bf16(wfl[q][k4], bh, A2[q], 0, 0, 0);
      }
    }
    if (um < 4) {
#pragma unroll
      for (int q = 0; q < 4; q++)
#pragma unroll
        for (int r = 0; r < 4; r++)
          gpart[wave][q][kq * 4 + r][um] = (A0[q][r] + A1[q][r]) + A2[q][r];
    }
    __syncthreads();
    // ---- epilogue: one LSTM cell per thread (wave 0)
    if (t < 64) {
      float g[4];
#pragma unroll
      for (int q = 0; q < 4; q++) {
        float a = xq[q][bbt];
#pragma unroll
        for (int w = 0; w < 4; w++) a += gpart[w][q][jj][bbt];
        g[q] = a;
      }
      float ig = sigm(g[0]), fg = sigm(g[1]), og = sigm(g[3]);
      float gt = tanhf(g[2]);
      float ct = fg * c_reg + ig * gt;
      float ht = og * tanhf(ct);
      bool upd = ubin_l[bbt] > 0.5f;
      float cn = upd ? ct : c_reg;
      float hn = upd ? ht : h_reg;
      c_reg = cn; h_reg = hn;
      u16 hhi, hlo; splitf(hn, hhi, hlo);
      uint32_t pk = ((uint32_t)hhi << 16) | (uint32_t)hlo;
      u64 wd = ((u64)(uint32_t)(s + 1) << 32) | (u64)pk;
      __hip_atomic_store(hwr + (long)np * 2048, wd, __ATOMIC_RELAXED, __HIP_MEMORY_SCOPE_AGENT);
      float pr = cn * wuh_l[jj];
      pr += __shfl_xor(pr, 4); pr += __shfl_xor(pr, 8);
      pr += __shfl_xor(pr, 16); pr += __shfl_xor(pr, 32);
      if (t < 4) {
        u64 pw = ((u64)(uint32_t)(s + 1) << 32) | (u64)__float_as_uint(pr);
        __hip_atomic_store(pwr + (long)np * 128, pw, __ATOMIC_RELAXED, __HIP_MEMORY_SCOPE_AGENT);
      }
      if (s == TLAST) outp[(long)(group * 4 + bbt) * 512 + slot * 16 + jj] = hn;
    }
    // no barrier here: next-iteration staging writes are separated from this
    // step's LDS reads by the two barriers above (all frag reads precede the
    // second barrier; epilogue LDS reads precede next step's first barrier).
  }
}

// ---------------- launcher ----------------
extern "C" void kernel_launch(void* const* d_in, const int* in_sizes, int n_in,
                              void* d_out, int out_size, void* d_ws, size_t ws_size,
                              hipStream_t stream) {
  const float* x      = (const float*)d_in[0];
  const float* conv_w = (const float*)d_in[1];
  const float* conv_b = (const float*)d_in[2];
  const float* gamma  = (const float*)d_in[3];
  const float* beta   = (const float*)d_in[4];
  const float* mean   = (const float*)d_in[5];
  const float* var    = (const float*)d_in[6];
  const float* w_ih   = (const float*)d_in[7];
  const float* w_hh   = (const float*)d_in[8];
  const float* b_ih   = (const float*)d_in[9];
  const float* b_hh   = (const float*)d_in[10];
  const float* w_uh   = (const float*)d_in[11];
  const float* b_uh   = (const float*)d_in[12];
  float* out = (float*)d_out;

  if (ws_size < WS_NEED) return;  // workspace too small: fail visibly via absmax

  char* w = (char*)d_ws;
  u64*   htag  = (u64*)(w + HTAG_OFF);
  u64*   ptag  = (u64*)(w + PTAG_OFF);
  float* xp    = (float*)(w + XP_OFF);
  u16*   xh    = (u16*)(w + XH_OFF);
  u16*   xl    = (u16*)(w + XL_OFF);
  u16*   xsh   = (u16*)(w + XSH_OFF);
  u16*   xsl   = (u16*)(w + XSL_OFF);
  u16*   wch   = (u16*)(w + WCH_OFF);
  u16*   wcl   = (u16*)(w + WCL_OFF);
  u16*   wihh  = (u16*)(w + WIHH_OFF);
  u16*   wihl  = (u16*)(w + WIHL_OFF);

  hipMemsetAsync(d_ws, 0, SYNC_BYTES, stream);  // all tags = 0 (never matches, want>=1)

  prep_kernel<<<19072, 256, 0, stream>>>(x, conv_w, w_ih, xh, xl, wch, wcl, wihh, wihl);

  // conv GEMM: M=256(f) N=16384 K=640 -> xs (relu+BN, bf16 hi/lo, [n][f])
  gemm_kernel<0><<<2 * 128, 256, 0, stream>>>(wch, wcl, xh, xl,
                                              conv_b, gamma, beta, mean, var,
                                              xsh, xsl, nullptr);
  // proj GEMM: M=2048(g) N=16384 K=256 -> xp fp32 [grp][g][t'][4b] (+ b_ih + b_hh)
  gemm_kernel<1><<<16 * 128, 256, 0, stream>>>(wihh, wihl, xsh, xsl,
                                               b_ih, b_hh, nullptr, nullptr, nullptr,
                                               nullptr, nullptr, xp);
  // persistent scan: 8 groups x 32 wgs, tag-in-data sync
  scan_kernel<<<GWG, 256, 0, stream>>>(xp, w_hh, w_uh, b_uh, htag, ptag, out);
}